// Round 1
// baseline (527.978 us; speedup 1.0000x reference)
//
#include <hip/hip_runtime.h>
#include <math.h>

#define B_ 32
#define D_ 16
#define T_ 1024
#define P_ 64
#define L_ 32
#define BIGV 1e30f

// ---- DPP helpers -----------------------------------------------------------
// update_dpp(old, src): lanes with invalid source (or masked row) get `old`
// (or 0 if bound_ctrl). All ctrl values are gfx9-family DPP encodings.
template<int CTRL, int ROW_MASK, bool BC>
__device__ __forceinline__ float dpp_mov(float old_, float src) {
  int o = __builtin_bit_cast(int, old_);
  int s = __builtin_bit_cast(int, src);
  int r = __builtin_amdgcn_update_dpp(o, s, CTRL, ROW_MASK, 0xf, BC);
  return __builtin_bit_cast(float, r);
}

// Inclusive prefix-sum over each 32-lane half of the wave.
// row_shr:1/2/4/8 within 16-lane rows, then bcast15 into rows 1 and 3.
__device__ __forceinline__ float scan_sum32(float v) {
  v += dpp_mov<0x111, 0xf, true>(0.f, v);   // row_shr:1
  v += dpp_mov<0x112, 0xf, true>(0.f, v);   // row_shr:2
  v += dpp_mov<0x114, 0xf, true>(0.f, v);   // row_shr:4
  v += dpp_mov<0x118, 0xf, true>(0.f, v);   // row_shr:8
  v += dpp_mov<0x142, 0xa, false>(0.f, v);  // row_bcast15 -> rows 1,3 only
  return v;
}

// Inclusive prefix-min over each 32-lane half (identity = BIG).
__device__ __forceinline__ float scan_min32(float v) {
  const float big = BIGV;
  v = fminf(v, dpp_mov<0x111, 0xf, false>(big, v));
  v = fminf(v, dpp_mov<0x112, 0xf, false>(big, v));
  v = fminf(v, dpp_mov<0x114, 0xf, false>(big, v));
  v = fminf(v, dpp_mov<0x118, 0xf, false>(big, v));
  v = fminf(v, dpp_mov<0x142, 0xa, false>(big, v));
  return v;
}

// ---- transpose: x[b][d][t] -> xT[b][t][d] (64B rows), plus x2[b][t] --------
__global__ void dtw_transpose(const float* __restrict__ x,
                              float* __restrict__ xT,
                              float* __restrict__ x2) {
  int gid = blockIdx.x * blockDim.x + threadIdx.x;   // 0 .. B*T-1
  if (gid >= B_ * T_) return;
  int b = gid >> 10;          // / T_
  int j = gid & (T_ - 1);
  float v[D_];
  float s = 0.f;
#pragma unroll
  for (int d = 0; d < D_; ++d) {
    v[d] = x[((size_t)(b * D_ + d)) * T_ + j];       // coalesced over j
    s = fmaf(v[d], v[d], s);
  }
  float4* dst = (float4*)(xT + (size_t)gid * D_);
#pragma unroll
  for (int q = 0; q < 4; ++q)
    dst[q] = make_float4(v[4*q], v[4*q+1], v[4*q+2], v[4*q+3]);
  x2[gid] = s;
}

// ---- main DTW kernel -------------------------------------------------------
// grid: 256 blocks of 256 threads. Block -> (b, 8 patterns); 32 lanes = L.
// Recurrence per column j:
//   m[i]   = w * min(D[i,j-1], D[i-1,j-1])
//   new[i] = c[i] + min(new[i-1], m[i]),  new[-1] = BIG
// Scan form: S = prefsum(c); new = S + prefmin(m + c - S).
__global__ __launch_bounds__(256) void dtw_kernel(
    const float* __restrict__ xT,     // [B][T][16]
    const float* __restrict__ x2a,    // [B][T]
    const float* __restrict__ patts,  // [P][D][L]
    const float* __restrict__ wp,     // scalar
    float* __restrict__ out)          // [B][P][T]
{
  const int tid = threadIdx.x;
  const int li  = tid & 31;                    // pattern position i
  const int grp = tid >> 5;                    // 0..7
  const int b   = blockIdx.x >> 3;
  const int p   = ((blockIdx.x & 7) << 3) + grp;
  const float w = wp[0];
  const bool lane0  = (li == 0);
  const bool lane31 = (li == 31);

  // pattern fragment in registers
  float pd[D_];
  float p2 = 0.f;
#pragma unroll
  for (int d = 0; d < D_; ++d) {
    pd[d] = patts[((size_t)p * D_ + d) * L_ + li];
    p2 = fmaf(pd[d], pd[d], p2);
  }

  const float* xrow  = xT  + ((size_t)b * T_) * D_;
  const float* x2row = x2a + (size_t)b * T_;
  float* orow = out + ((size_t)(b * P_ + p)) * T_;

  float dcur;
  // ---- j = 0: pure cumsum column ----
  {
    const float* xp = xrow;
    float a0 = 0.f, a1 = 0.f, a2 = 0.f, a3 = 0.f;
#pragma unroll
    for (int d = 0; d < D_; d += 4) {
      a0 = fmaf(xp[d + 0], pd[d + 0], a0);
      a1 = fmaf(xp[d + 1], pd[d + 1], a1);
      a2 = fmaf(xp[d + 2], pd[d + 2], a2);
      a3 = fmaf(xp[d + 3], pd[d + 3], a3);
    }
    float dot = (a0 + a1) + (a2 + a3);
    float c = fmaf(-2.f, dot, x2row[0] + p2);
    dcur = scan_sum32(c);
    if (lane31) orow[0] = sqrtf(dcur);
  }

  // ---- j = 1 .. T-1 ----
#pragma unroll 2
  for (int j = 1; j < T_; ++j) {
    const float* xp = xrow + (size_t)j * D_;   // wave-uniform -> s_load
    float a0 = 0.f, a1 = 0.f, a2 = 0.f, a3 = 0.f;
#pragma unroll
    for (int d = 0; d < D_; d += 4) {
      a0 = fmaf(xp[d + 0], pd[d + 0], a0);
      a1 = fmaf(xp[d + 1], pd[d + 1], a1);
      a2 = fmaf(xp[d + 2], pd[d + 2], a2);
      a3 = fmaf(xp[d + 3], pd[d + 3], a3);
    }
    float dot = (a0 + a1) + (a2 + a3);
    float c = fmaf(-2.f, dot, x2row[j] + p2);

    // D[i-1, j-1]: shift down by one lane across the wave, fix group starts
    float pu = dpp_mov<0x138, 0xf, false>(BIGV, dcur);   // wave_shr:1
    pu = lane0 ? BIGV : pu;
    float m = w * fminf(dcur, pu);

    float S = scan_sum32(c);
    float e = (m + c) - S;
    float M = scan_min32(e);
    dcur = S + M;

    if (lane31) orow[j] = sqrtf(dcur);
  }
}

extern "C" void kernel_launch(void* const* d_in, const int* in_sizes, int n_in,
                              void* d_out, int out_size, void* d_ws, size_t ws_size,
                              hipStream_t stream) {
  const float* x     = (const float*)d_in[0];
  const float* patts = (const float*)d_in[1];
  const float* w     = (const float*)d_in[2];
  float* out = (float*)d_out;

  float* xT = (float*)d_ws;                  // B*T*16 floats = 2 MiB
  float* x2 = xT + (size_t)B_ * T_ * D_;     // B*T floats

  dtw_transpose<<<(B_ * T_ + 255) / 256, 256, 0, stream>>>(x, xT, x2);
  dtw_kernel<<<B_ * (P_ / 8), 256, 0, stream>>>(xT, x2, patts, w, out);
}

// Round 2
// 315.293 us; speedup vs baseline: 1.6746x; 1.6746x over previous
//
#include <hip/hip_runtime.h>
#include <math.h>

#define B_ 32
#define D_ 16
#define T_ 1024
#define P_ 64
#define L_ 32
#define XSTR 20          // floats per transposed column row: 16 x + 1 x2 + pad
#define BIGV 1e30f

// ---- DPP helpers -----------------------------------------------------------
template<int CTRL, int ROW_MASK, bool BC>
__device__ __forceinline__ float dpp_mov(float old_, float src) {
  int o = __builtin_bit_cast(int, old_);
  int s = __builtin_bit_cast(int, src);
  int r = __builtin_amdgcn_update_dpp(o, s, CTRL, ROW_MASK, 0xf, BC);
  return __builtin_bit_cast(float, r);
}

// Inclusive prefix-sum over each 32-lane half of the wave.
__device__ __forceinline__ float scan_sum32(float v) {
  v += dpp_mov<0x111, 0xf, true>(0.f, v);   // row_shr:1
  v += dpp_mov<0x112, 0xf, true>(0.f, v);   // row_shr:2
  v += dpp_mov<0x114, 0xf, true>(0.f, v);   // row_shr:4
  v += dpp_mov<0x118, 0xf, true>(0.f, v);   // row_shr:8
  v += dpp_mov<0x142, 0xa, false>(0.f, v);  // row_bcast15 -> rows 1,3
  return v;
}

// Inclusive prefix-min over each 32-lane half (identity = BIG).
__device__ __forceinline__ float scan_min32(float v) {
  const float big = BIGV;
  v = fminf(v, dpp_mov<0x111, 0xf, false>(big, v));
  v = fminf(v, dpp_mov<0x112, 0xf, false>(big, v));
  v = fminf(v, dpp_mov<0x114, 0xf, false>(big, v));
  v = fminf(v, dpp_mov<0x118, 0xf, false>(big, v));
  v = fminf(v, dpp_mov<0x142, 0xa, false>(big, v));
  return v;
}

// ---- transpose: x[b][d][t] -> xT[b][t][XSTR] rows (x[0..15], x2 at [16]) ---
__global__ void dtw_transpose(const float* __restrict__ x,
                              float* __restrict__ xT) {
  int gid = blockIdx.x * blockDim.x + threadIdx.x;   // 0 .. B*T-1
  if (gid >= B_ * T_) return;
  int b = gid >> 10;          // / T_
  int j = gid & (T_ - 1);
  float v[D_];
  float s = 0.f;
#pragma unroll
  for (int d = 0; d < D_; ++d) {
    v[d] = x[((size_t)(b * D_ + d)) * T_ + j];       // coalesced over j
    s = fmaf(v[d], v[d], s);
  }
  float* row = xT + (size_t)gid * XSTR;
  float4* dst = (float4*)row;
#pragma unroll
  for (int q = 0; q < 4; ++q)
    dst[q] = make_float4(v[4*q], v[4*q+1], v[4*q+2], v[4*q+3]);
  row[16] = s;
}

struct XCol { float4 v0, v1, v2, v3; float s; };

// ---- main DTW kernel -------------------------------------------------------
// Block -> (b, 8 patterns); 32 lanes = L. 3-deep VMEM-pipelined x loads.
__global__ __launch_bounds__(256) void dtw_kernel(
    const float* __restrict__ xT,     // [B][T][XSTR]
    const float* __restrict__ patts,  // [P][D][L]
    const float* __restrict__ wp,     // scalar
    float* __restrict__ out)          // [B][P][T]
{
  const int tid = threadIdx.x;
  const int li  = tid & 31;                    // pattern position i
  const int grp = tid >> 5;                    // 0..7
  const int b   = blockIdx.x >> 3;
  const int p   = ((blockIdx.x & 7) << 3) + grp;
  const float w = wp[0];
  const bool lane0  = (li == 0);
  const bool lane31 = (li == 31);

  // Divergent-looking zero: defeats SMEM scalarization of the x loads so they
  // stay on the in-order vmcnt path (pipelinable with fine-grained waits).
  const int zdiv = __builtin_amdgcn_mbcnt_lo(0u, 0u);   // == 0 for all lanes

  // pattern fragment in registers
  float pd[D_];
  float p2 = 0.f;
#pragma unroll
  for (int d = 0; d < D_; ++d) {
    pd[d] = patts[((size_t)p * D_ + d) * L_ + li];
    p2 = fmaf(pd[d], pd[d], p2);
  }

  const float* xrow = xT + ((size_t)b * T_) * XSTR;
  float* orow = out + ((size_t)(b * P_ + p)) * T_;

  auto lcol = [&](int j, XCol& X) {
    const float* bp = xrow + (size_t)j * XSTR + zdiv;
    X.v0 = *(const float4*)(bp + 0);
    X.v1 = *(const float4*)(bp + 4);
    X.v2 = *(const float4*)(bp + 8);
    X.v3 = *(const float4*)(bp + 12);
    X.s  = bp[16];
  };

  auto costc = [&](const XCol& X) -> float {
    float a0 = 0.f, a1 = 0.f, a2 = 0.f, a3 = 0.f;
    a0 = fmaf(X.v0.x, pd[0],  a0); a1 = fmaf(X.v0.y, pd[1],  a1);
    a2 = fmaf(X.v0.z, pd[2],  a2); a3 = fmaf(X.v0.w, pd[3],  a3);
    a0 = fmaf(X.v1.x, pd[4],  a0); a1 = fmaf(X.v1.y, pd[5],  a1);
    a2 = fmaf(X.v1.z, pd[6],  a2); a3 = fmaf(X.v1.w, pd[7],  a3);
    a0 = fmaf(X.v2.x, pd[8],  a0); a1 = fmaf(X.v2.y, pd[9],  a1);
    a2 = fmaf(X.v2.z, pd[10], a2); a3 = fmaf(X.v2.w, pd[11], a3);
    a0 = fmaf(X.v3.x, pd[12], a0); a1 = fmaf(X.v3.y, pd[13], a1);
    a2 = fmaf(X.v3.z, pd[14], a2); a3 = fmaf(X.v3.w, pd[15], a3);
    float dot = (a0 + a1) + (a2 + a3);
    return fmaf(-2.f, dot, X.s + p2);
  };

  float dcur;
  auto step = [&](int j, const XCol& X) {
    float c = costc(X);
    // D[i-1, j-1]: shift down one lane across the wave, fix group starts
    float pu = dpp_mov<0x138, 0xf, false>(BIGV, dcur);   // wave_shr:1
    pu = lane0 ? BIGV : pu;
    float m = w * fminf(dcur, pu);
    float S = scan_sum32(c);
    float M = scan_min32(m + (c - S));
    dcur = S + M;
    if (lane31) orow[j] = sqrtf(dcur);
  };

  XCol A, B, C;
  lcol(0, A); lcol(1, B); lcol(2, C);

  // ---- j = 0: pure cumsum column ----
  {
    float c = costc(A);
    dcur = scan_sum32(c);
    if (lane31) orow[0] = sqrtf(dcur);
  }
  lcol(3, A);

  // ---- j = 1 .. 1023, unrolled x3 with rotating prefetch (distance 3) ----
  for (int k = 0; k < 341; ++k) {
    int j = 1 + 3 * k;
    int j3 = j + 3 > 1023 ? 1023 : j + 3;
    int j4 = j + 4 > 1023 ? 1023 : j + 4;
    int j5 = j + 5 > 1023 ? 1023 : j + 5;
    step(j,     B);  lcol(j3, B);
    step(j + 1, C);  lcol(j4, C);
    step(j + 2, A);  lcol(j5, A);
  }
}

extern "C" void kernel_launch(void* const* d_in, const int* in_sizes, int n_in,
                              void* d_out, int out_size, void* d_ws, size_t ws_size,
                              hipStream_t stream) {
  const float* x     = (const float*)d_in[0];
  const float* patts = (const float*)d_in[1];
  const float* w     = (const float*)d_in[2];
  float* out = (float*)d_out;

  float* xT = (float*)d_ws;                  // B*T*XSTR floats = 2.62 MB

  dtw_transpose<<<(B_ * T_ + 255) / 256, 256, 0, stream>>>(x, xT);
  dtw_kernel<<<B_ * (P_ / 8), 256, 0, stream>>>(xT, patts, w, out);
}